// Round 5
// baseline (245.828 us; speedup 1.0000x reference)
//
#include <hip/hip_runtime.h>
#include <hip/hip_bf16.h>

typedef __attribute__((ext_vector_type(8))) short short8;
typedef __attribute__((ext_vector_type(16))) float f32x16;
typedef __attribute__((ext_vector_type(4))) float f32x4;

static constexpr int NN = 64;
static constexpr int C  = 128;
static constexpr int H  = 56;
static constexpr int W  = 56;
static constexpr int HP = 58;          // padded spatial extent
static constexpr int ROWB = HP * 256;  // padded row stride in bytes (NHWC bf16)

__device__ __forceinline__ void gload16(const void* g, void* l) {
    __builtin_amdgcn_global_load_lds(
        (const __attribute__((address_space(1))) unsigned int*)g,
        (__attribute__((address_space(3))) unsigned int*)l, 16, 0, 0);
}

__device__ __forceinline__ f32x16 mfma32(short8 a, short8 b, f32x16 c) {
    return __builtin_amdgcn_mfma_f32_32x32x16_bf16(a, b, c, 0, 0, 0);
}

// ---------------------------------------------------------------------------
// Pack weights into MFMA-fragment order:
//   Wp2[((tap*8 + ks)*2 + hi)*128 + o][j]  (bf16, j=0..7), c = ks*16+hi*8+j
// ---------------------------------------------------------------------------
__global__ __launch_bounds__(128)
void pack_weights(const float* __restrict__ w, const float* __restrict__ g,
                  const float* __restrict__ b, const float* __restrict__ m,
                  const float* __restrict__ v, __hip_bfloat16* __restrict__ Wp2,
                  float* __restrict__ shift)
{
    int o = blockIdx.x;
    int c = threadIdx.x;
    float scale = g[o] * rsqrtf(v[o] + 1e-5f);
    if (c == 0) shift[o] = b[o] - m[o] * scale;
    const float* ws = w + ((size_t)o * C + c) * 9;
    int ks = c >> 4, hi = (c >> 3) & 1, j = c & 7;
    #pragma unroll
    for (int tap = 0; tap < 9; ++tap) {
        size_t idx = ((((size_t)tap * 8 + ks) * 2 + hi) * 128 + o) * 8 + j;
        Wp2[idx] = __float2bfloat16(ws[tap] * scale);
    }
}

// ---------------------------------------------------------------------------
// NCHW fp32 -> padded NHWC bf16 (interior only; halo zeroed separately).
// ---------------------------------------------------------------------------
__global__ __launch_bounds__(256)
void transform_x(const float* __restrict__ x, __hip_bfloat16* __restrict__ Xp)
{
    __shared__ float t[C * 57];
    int bid = blockIdx.x;
    int n = bid / H, h = bid % H;
    int tid = threadIdx.x;

    #pragma unroll
    for (int i = 0; i < 7; ++i) {
        int idx4 = i * 256 + tid;
        int c  = idx4 / 14;
        int wq = (idx4 % 14) * 4;
        const float* p = x + ((size_t)(n * C + c)) * (H * W) + h * W + wq;
        float4 vv = *(const float4*)p;
        t[c * 57 + wq + 0] = vv.x;
        t[c * 57 + wq + 1] = vv.y;
        t[c * 57 + wq + 2] = vv.z;
        t[c * 57 + wq + 3] = vv.w;
    }
    __syncthreads();
    #pragma unroll
    for (int i = 0; i < 28; ++i) {
        int idx = i * 256 + tid;
        int c = idx & 127, w = idx >> 7;
        float vv = t[c * 57 + w];
        Xp[(((size_t)n * HP + (h + 1)) * HP + (w + 1)) * C + c] = __float2bfloat16(vv);
    }
}

// ---------------------------------------------------------------------------
// Zero only the halo of a padded NHWC buffer.
// ---------------------------------------------------------------------------
__global__ __launch_bounds__(256)
void zero_halo(__hip_bfloat16* __restrict__ buf)
{
    int idx = blockIdx.x * 256 + threadIdx.x;
    int n = idx / (228 * 16);
    int rem = idx % (228 * 16);
    int p = rem >> 4, l = rem & 15;
    int y, xq;
    if (p < 58)       { y = 0;  xq = p; }
    else if (p < 116) { y = 57; xq = p - 58; }
    else { int q = p - 116; y = 1 + (q >> 1); xq = (q & 1) * 57; }
    short8* dst = (short8*)(buf + (((size_t)n * HP + y) * HP + xq) * C + l * 8);
    *dst = short8{0,0,0,0,0,0,0,0};
}

// ---------------------------------------------------------------------------
// Implicit-GEMM 3x3 conv.  Block = 256 thr (4 waves), 2 output rows x O=128.
// Wave (wm,mh): row h0+wm, m-half mh -> 32 m x 128 o tile = 4 x f32x16 acc.
// X: 3-slot LDS ring (XOR-swizzled via pre-swizzled gload_lds source).
// W: direct from L1/L2 with 2-deep half-tap register prefetch, PINNED by
// sched_barrier(0) fences so the scheduler cannot sink the loads (round-4
// post-mortem: without fences, VGPR=84 proved the pipeline was discarded).
// ---------------------------------------------------------------------------
template<int WHICH>
__global__ __launch_bounds__(256, 2)
void conv3x3_kernel(const __hip_bfloat16* __restrict__ Xp,
                    const __hip_bfloat16* __restrict__ Wp2,
                    const float* __restrict__ shift,
                    const float* __restrict__ ident,
                    void* __restrict__ outp)
{
    __shared__ char s_x[3 * 16384 + 1024];   // 3 ring slots + over-read pad

    const int tid  = threadIdx.x;
    const int wave = tid >> 6;
    const int lane = tid & 63;
    const int lr5  = lane & 31;
    const int hi   = lane >> 5;
    const int wm   = wave >> 1;      // output row within block
    const int mh   = wave & 1;       // m-half

    const int bid0 = blockIdx.x;
    const int bid  = (bid0 & 7) * 224 + (bid0 >> 3);   // XCD chunk swizzle
    const int n = bid / 28, h0 = (bid % 28) * 2;

    const char* xbase = (const char*)Xp + ((size_t)n * HP + h0) * ROWB;

    // prologue: stage padded rows 0..2 -> slots 0..2 (48 x 1KB)
    #pragma unroll
    for (int i = 0; i < 12; ++i) {
        int t = wave + i * 4;            // 0..47
        int q = t >> 4, blk = t & 15;
        int dst = blk * 1024 + lane * 16;
        int src = dst ^ (((dst >> 8) & 15) << 4);
        gload16(xbase + (size_t)q * ROWB + src, s_x + q * 16384 + blk * 1024);
    }

    const __hip_bfloat16* wlane = Wp2 + hi * 1024 + lr5 * 8;

    short8 wqA[4][4], wqB[4][4];
    f32x16 acc[4];
    #pragma unroll
    for (int i = 0; i < 4; ++i)
        acc[i] = f32x16{0,0,0,0,0,0,0,0,0,0,0,0,0,0,0,0};

#define SB() __builtin_amdgcn_sched_barrier(0)

#define WLOAD(BUF, HT) { \
    _Pragma("unroll") for (int i_ = 0; i_ < 4; ++i_) { \
        const __hip_bfloat16* p_ = wlane + ((HT) * 4 + i_) * 2048; \
        _Pragma("unroll") for (int of_ = 0; of_ < 4; ++of_) \
            BUF[i_][of_] = *(const short8*)(p_ + of_ * 256); } }

#define COMPUTE(BUF, HT) { \
    constexpr int tap_ = (HT) >> 1; \
    constexpr int kw_ = tap_ % 3, kh_ = tap_ / 3; \
    const int sb_ = ((kh_ + wm) % 3) * 16384; \
    const int row_ = mh * 32 + lr5 + kw_; \
    const int rb_ = row_ * 256, sw_ = (row_ & 15) << 4; \
    _Pragma("unroll") for (int i_ = 0; i_ < 4; ++i_) { \
        int ks_ = ((HT) & 1) * 4 + i_; \
        short8 xa_ = *(const short8*)(s_x + sb_ + rb_ + ((ks_ * 32 + hi * 16) ^ sw_)); \
        _Pragma("unroll") for (int of_ = 0; of_ < 4; ++of_) { \
            if (WHICH == 0) acc[of_] = mfma32(xa_, BUF[i_][of_], acc[of_]); \
            else            acc[of_] = mfma32(BUF[i_][of_], xa_, acc[of_]); } } }

    WLOAD(wqA, 0);
    __syncthreads();
    // ---- kh = 0 (half-taps 0..5) ----
    WLOAD(wqB, 1);  SB(); COMPUTE(wqA, 0);  SB();
    WLOAD(wqA, 2);  SB(); COMPUTE(wqB, 1);  SB();
    WLOAD(wqB, 3);  SB(); COMPUTE(wqA, 2);  SB();
    WLOAD(wqA, 4);  SB(); COMPUTE(wqB, 3);  SB();
    WLOAD(wqB, 5);  SB(); COMPUTE(wqA, 4);  SB();
    WLOAD(wqA, 6);  SB(); COMPUTE(wqB, 5);  SB();
    __syncthreads();
    // ---- kh = 1 (half-taps 6..11); prefetch padded row 3 -> slot 0 ----
    #pragma unroll
    for (int i = 0; i < 4; ++i) {
        int blk = wave + i * 4;          // 0..15
        int dst = blk * 1024 + lane * 16;
        int src = dst ^ (((dst >> 8) & 15) << 4);
        gload16(xbase + (size_t)3 * ROWB + src, s_x + blk * 1024);
    }
    SB();
    WLOAD(wqB, 7);  SB(); COMPUTE(wqA, 6);  SB();
    WLOAD(wqA, 8);  SB(); COMPUTE(wqB, 7);  SB();
    WLOAD(wqB, 9);  SB(); COMPUTE(wqA, 8);  SB();
    WLOAD(wqA, 10); SB(); COMPUTE(wqB, 9);  SB();
    WLOAD(wqB, 11); SB(); COMPUTE(wqA, 10); SB();
    WLOAD(wqA, 12); SB(); COMPUTE(wqB, 11); SB();
    __syncthreads();
    // ---- kh = 2 (half-taps 12..17) ----
    WLOAD(wqB, 13); SB(); COMPUTE(wqA, 12); SB();
    WLOAD(wqA, 14); SB(); COMPUTE(wqB, 13); SB();
    WLOAD(wqB, 15); SB(); COMPUTE(wqA, 14); SB();
    WLOAD(wqA, 16); SB(); COMPUTE(wqB, 15); SB();
    WLOAD(wqB, 17); SB(); COMPUTE(wqA, 16); SB();
    COMPUTE(wqB, 17);
#undef WLOAD
#undef COMPUTE
#undef SB

    // C/D layout (32x32): col = lane&31, row = (r&3) + 8*(r>>2) + 4*hi
    if (WHICH == 0) {
        __hip_bfloat16* o1 = (__hip_bfloat16*)outp;
        size_t rowb = ((size_t)n * HP + (h0 + wm + 1)) * HP;
        #pragma unroll
        for (int of = 0; of < 4; ++of) {
            int o = of * 32 + lr5;
            float sh = shift[o];
            #pragma unroll
            for (int r = 0; r < 16; ++r) {
                int m = mh * 32 + 4 * hi + (r & 3) + 8 * (r >> 2);
                if (m < W) {
                    float f = acc[of][r] + sh;
                    f = f > 0.f ? f : 0.f;
                    o1[(rowb + m + 1) * C + o] = __float2bfloat16(f);
                }
            }
        }
    } else {
        float* o2 = (float*)outp;
        int h = h0 + wm;
        int m = mh * 32 + lr5;
        if (m < W) {
            #pragma unroll
            for (int of = 0; of < 4; ++of) {
                #pragma unroll
                for (int q = 0; q < 4; ++q) {
                    f32x4 sh = *(const f32x4*)(shift + of * 32 + 4 * hi + 8 * q);
                    #pragma unroll
                    for (int j = 0; j < 4; ++j) {
                        int o = of * 32 + 4 * hi + 8 * q + j;
                        size_t idx = ((size_t)(n * C + o) * H + h) * W + m;
                        float f = acc[of][q * 4 + j] + sh[j] + ident[idx];
                        o2[idx] = f > 0.f ? f : 0.f;
                    }
                }
            }
        }
    }
}

// ---------------------------------------------------------------------------
extern "C" void kernel_launch(void* const* d_in, const int* in_sizes, int n_in,
                              void* d_out, int out_size, void* d_ws, size_t ws_size,
                              hipStream_t stream)
{
    const float* x  = (const float*)d_in[0];
    const float* w1 = (const float*)d_in[1];
    const float* g1 = (const float*)d_in[2];
    const float* b1 = (const float*)d_in[3];
    const float* m1 = (const float*)d_in[4];
    const float* v1 = (const float*)d_in[5];
    const float* w2 = (const float*)d_in[6];
    const float* g2 = (const float*)d_in[7];
    const float* b2 = (const float*)d_in[8];
    const float* m2 = (const float*)d_in[9];
    const float* v2 = (const float*)d_in[10];
    float* out = (float*)d_out;

    char* ws = (char*)d_ws;
    const size_t PADBUF = (size_t)NN * HP * HP * C * 2;    // 55,107,584 B
    const size_t WBUF   = (size_t)9 * 8 * 2 * 128 * 8 * 2; // 294,912 B
    size_t oX  = 0;
    size_t oY  = oX + PADBUF + 32768;    // slack for staging over-read
    size_t oW1 = oY + PADBUF + 32768;
    size_t oW2 = oW1 + WBUF;
    size_t oS1 = oW2 + WBUF;
    size_t oS2 = oS1 + 512;

    __hip_bfloat16* Xp  = (__hip_bfloat16*)(ws + oX);
    __hip_bfloat16* Y1  = (__hip_bfloat16*)(ws + oY);
    __hip_bfloat16* W1p = (__hip_bfloat16*)(ws + oW1);
    __hip_bfloat16* W2p = (__hip_bfloat16*)(ws + oW2);
    float* s1 = (float*)(ws + oS1);
    float* s2 = (float*)(ws + oS2);

    zero_halo<<<912, 256, 0, stream>>>(Xp);
    zero_halo<<<912, 256, 0, stream>>>(Y1);

    pack_weights<<<128, 128, 0, stream>>>(w1, g1, b1, m1, v1, W1p, s1);
    pack_weights<<<128, 128, 0, stream>>>(w2, g2, b2, m2, v2, W2p, s2);
    transform_x<<<NN * H, 256, 0, stream>>>(x, Xp);

    conv3x3_kernel<0><<<NN * 28, 256, 0, stream>>>(Xp, W1p, s1, nullptr, (void*)Y1);
    conv3x3_kernel<1><<<NN * 28, 256, 0, stream>>>(Y1, W2p, s2, x, (void*)out);
}